// Round 10
// baseline (161.853 us; speedup 1.0000x reference)
//
#include <hip/hip_runtime.h>
#include <hip/hip_bf16.h>

#define C 64          // C_IN == C_OUT == 64
#define BSH 7         // bucket shift: 128 nodes per bucket
#define BN  128       // nodes per bucket
#define NPART 8       // partitions == XCDs (agg node->block mapping)
#define PBUK 98       // buckets per partition (8*98=784 >= 782)
#define PS (PBUK*BN)  // nodes per partition = 12544
#define NBUK 784      // total buckets
#define EPB2 8192     // edges per k_bin block (256 thr x 32)
#define BCAP 2560     // bucket capacity (mean 2046, ~12 sigma)
#define S2P_GRID 512  // persistent blocks for k_sort2proj (2/CU, work-counter balanced)

typedef __attribute__((ext_vector_type(8))) short bh8;    // 8 bf16 (MFMA A/B frag)
typedef __attribute__((ext_vector_type(4))) float fx4;    // MFMA C/D frag
typedef __attribute__((ext_vector_type(4))) int   ix4;
typedef __attribute__((ext_vector_type(8))) unsigned short us8;

__device__ __forceinline__ unsigned short f2bf(float f) {  // RNE f32 -> bf16
    unsigned u = __float_as_uint(f);
    u += 0x7FFF + ((u >> 16) & 1);
    return (unsigned short)(u >> 16);
}
__device__ __forceinline__ float bf2f(unsigned short h) {
    return __uint_as_float(((unsigned)h) << 16);
}
#define BF2L(u) __uint_as_float((u) << 16)
#define BF2H(u) __uint_as_float((u) & 0xFFFF0000u)

// ---------------- 1: single-pass 784-way bin: edges -> pe[bucket*BCAP + rank] -------------
// Round-6 configuration verbatim (best measured): 196 blocks x 256 thr x 32 edges.
// Block 0 also builds the split-bf16 W fragments for k_sort2proj.
__global__ __launch_bounds__(256) void k_bin(const int* __restrict__ row, const int* __restrict__ col,
                                             int* __restrict__ bcur, int* __restrict__ pe, int E,
                                             const float* __restrict__ W, bh8* __restrict__ Wf) {
    __shared__ int h[NBUK];
    __shared__ int cur[NBUK];
    int tid = threadIdx.x;
    for (int i = tid; i < NBUK; i += 256) h[i] = 0;
    __syncthreads();

    int base = blockIdx.x * EPB2;
    int cs[32], rs[32];
    if (base + EPB2 <= E) {
#pragma unroll
        for (int ch = 0; ch < 8; ch++) {           // coalesced: lanes contiguous 16B
            int idx = base + ch * 1024 + (tid << 2);
            ix4 c = *(const ix4*)(col + idx);
            ix4 r = *(const ix4*)(row + idx);
#pragma unroll
            for (int k = 0; k < 4; k++) { cs[ch * 4 + k] = c[k]; rs[ch * 4 + k] = r[k]; }
        }
    } else {
#pragma unroll
        for (int i = 0; i < 32; i++) {
            int idx = base + (i >> 2) * 1024 + (tid << 2) + (i & 3);
            cs[i] = (idx < E) ? col[idx] : -1;
            rs[i] = (idx < E) ? row[idx] : 0;
        }
    }
#pragma unroll
    for (int i = 0; i < 32; i++)
        if (cs[i] >= 0) atomicAdd(&h[cs[i] >> BSH], 1);
    __syncthreads();
    for (int i = tid; i < NBUK; i += 256) {
        int c = h[i];
        cur[i] = (c > 0) ? atomicAdd(&bcur[i], c) : 0;
    }
    __syncthreads();
#pragma unroll
    for (int i = 0; i < 32; i++) {
        if (cs[i] >= 0) {
            int b = cs[i] >> BSH;
            int pos = atomicAdd(&cur[b], 1);
            if (pos < BCAP)
                pe[(size_t)b * BCAP + pos] = ((cs[i] & (BN - 1)) << 17) | rs[i];  // trel<<17|src
        }
    }

    // block 0: build Wf (split-bf16 W fragments); ready before k_sort2proj runs
    if (blockIdx.x == 0) {
        for (int it = tid; it < 512; it += 256) {
            int lane = it & 63;
            int th = it >> 6;        // t*2+h, 0..7
            int t = th >> 1, hh = th & 1;
            int m16 = lane & 15, q = lane >> 4;
            int n = t * 16 + m16;
            bh8 hi, lo;
#pragma unroll
            for (int j = 0; j < 8; j++) {
                int k = 32 * hh + q * 8 + j;
                float w = W[k * 64 + n];
                unsigned short hb = f2bf(w);
                hi[j] = (short)hb;
                lo[j] = (short)f2bf(w - bf2f(hb));
            }
            Wf[(th * 2 + 0) * 64 + lane] = hi;
            Wf[(th * 2 + 1) * 64 + lane] = lo;
        }
    }
}

// ---------------- 2: fused bucket->CSR + MFMA projection (persistent blocks) --------------
// Round-6 body (two-pass pe read: hist, then counting-sort scatter) with three changes:
//  (a) persistent blocks (512) pulling buckets off a global work counter -> kills the
//      784-block 3.06/CU quantization tail (~1/4 of CUs ran a 4th block);
//  (b) wave-level shfl scan (2 barriers) replaces the 14-barrier Hillis-Steele scan;
//  (c) Wf B-fragment loads hoisted out of the bucket loop.
// Loop statically bounded (iter < NBUK) so termination is guaranteed regardless of wcnt
// state. es/y output bit-identical to round 6 (same per-bucket scatter order).
__global__ __launch_bounds__(256) void k_sort2proj(const int* __restrict__ pe, const int* __restrict__ bcur,
                                                   int* __restrict__ wcnt,
                                                   int* __restrict__ es, int* __restrict__ rowptr,
                                                   int* __restrict__ deg, const float* __restrict__ x,
                                                   const bh8* __restrict__ Wf, unsigned short* __restrict__ y,
                                                   int N) {
    __shared__ int cnt[BN];
    __shared__ int cur[BN];
    __shared__ int dsh[BN];
    __shared__ int wtot;
    __shared__ int bsel;
    __shared__ unsigned short stage[4][32][C];    // 16 KB (per-wave private)

    int tid = threadIdx.x;
    int lane = tid & 63;
    int wave = tid >> 6;
    int m16 = lane & 15;
    int q   = lane >> 4;

    // (c) hoisted: B fragments are bucket-independent
    bh8 Bhi[4][2], Blo[4][2];
#pragma unroll
    for (int t = 0; t < 4; t++) {
#pragma unroll
        for (int h = 0; h < 2; h++) {
            Bhi[t][h] = Wf[((t * 2 + h) * 2 + 0) * 64 + lane];  // coalesced dwordx4
            Blo[t][h] = Wf[((t * 2 + h) * 2 + 1) * 64 + lane];
        }
    }

    for (int iter = 0; iter < NBUK; ++iter) {
        if (tid == 0) bsel = atomicAdd(wcnt, 1);
        if (tid < BN) cnt[tid] = 0;
        __syncthreads();
        int b = bsel;
        if (b >= NBUK) break;                      // uniform: bsel is block-shared

        int m = bcur[b]; m = m < BCAP ? m : BCAP;
        size_t s0 = (size_t)b * BCAP;
        const int* peb = pe + s0;

        // pass A: histogram (vectorized read)
        for (int e0 = tid * 4; e0 < m; e0 += 1024) {
            if (e0 + 4 <= m) {
                ix4 a = *(const ix4*)(peb + e0);
#pragma unroll
                for (int k = 0; k < 4; k++) atomicAdd(&cnt[a[k] >> 17], 1);
            } else {
                for (int e = e0; e < m; e++) atomicAdd(&cnt[peb[e] >> 17], 1);
            }
        }
        __syncthreads();

        // (b) wave-level scan: waves 0,1 hold cnt[0..63], cnt[64..127]
        int v = 0, sc = 0;
        if (tid < BN) {
            v = cnt[tid];
            sc = v;
#pragma unroll
            for (int off = 1; off < 64; off <<= 1) {
                int t = __shfl_up(sc, off, 64);
                if (lane >= off) sc += t;
            }
            if (tid == 63) wtot = sc;             // total of wave 0
        }
        __syncthreads();
        if (tid < BN) {
            int incl = sc + ((tid >= 64) ? wtot : 0);
            int excl = incl - v;
            cur[tid] = (int)s0 + excl;
            dsh[tid] = v;
            int node = b * BN + tid;
            if (node < N) { rowptr[node] = (int)s0 + excl; deg[node] = v; }
        }
        __syncthreads();

        // pass B: counting-sort scatter (pe re-read from L2)
        for (int e0 = tid * 4; e0 < m; e0 += 1024) {
            if (e0 + 4 <= m) {
                ix4 a = *(const ix4*)(peb + e0);
#pragma unroll
                for (int k = 0; k < 4; k++) {
                    int pos = atomicAdd(&cur[a[k] >> 17], 1);
                    es[pos] = a[k] & 0x1FFFF;
                }
            } else {
                for (int e = e0; e < m; e++) {
                    int p = peb[e];
                    int pos = atomicAdd(&cur[p >> 17], 1);
                    es[pos] = p & 0x1FFFF;
                }
            }
        }
        __syncthreads();

        // ---- phase 2: projection of nodes b*BN .. b*BN+127 ----
        int rowbase = b * BN + wave * 32;
#pragma unroll
        for (int tt = 0; tt < 2; tt++) {
            int m0 = rowbase + tt * 16;
            if (m0 < N) {
                int mrow = m0 + m16;
                int mc = mrow < N ? mrow : (N - 1);

                bh8 Ahi[2], Alo[2];
#pragma unroll
                for (int h = 0; h < 2; h++) {
                    const fx4* p = (const fx4*)(x + (size_t)mc * C + 32 * h + q * 8);
                    fx4 v0 = __builtin_nontemporal_load(p);
                    fx4 v1 = __builtin_nontemporal_load(p + 1);
                    float vs[8] = {v0[0], v0[1], v0[2], v0[3], v1[0], v1[1], v1[2], v1[3]};
#pragma unroll
                    for (int j = 0; j < 8; j++) {
                        unsigned short hb = f2bf(vs[j]);
                        Ahi[h][j] = (short)hb;
                        Alo[h][j] = (short)f2bf(vs[j] - bf2f(hb));
                    }
                }

                float dv[4];
#pragma unroll
                for (int r = 0; r < 4; r++) {
                    int lr = wave * 32 + tt * 16 + q * 4 + r;  // local row
                    dv[r] = rsqrtf((float)(dsh[lr] + 1));
                }

#pragma unroll
                for (int t = 0; t < 4; t++) {
                    fx4 acc = {0.f, 0.f, 0.f, 0.f};
#pragma unroll
                    for (int h = 0; h < 2; h++) {
                        acc = __builtin_amdgcn_mfma_f32_16x16x32_bf16(Ahi[h], Bhi[t][h], acc, 0, 0, 0);
                        acc = __builtin_amdgcn_mfma_f32_16x16x32_bf16(Ahi[h], Blo[t][h], acc, 0, 0, 0);
                        acc = __builtin_amdgcn_mfma_f32_16x16x32_bf16(Alo[h], Bhi[t][h], acc, 0, 0, 0);
                    }
#pragma unroll
                    for (int r = 0; r < 4; r++)
                        stage[wave][tt * 16 + q * 4 + r][t * 16 + m16] = f2bf(acc[r] * dv[r]);
                }
            }
        }
        // wave-local stage->global, 16 B/lane coalesced (same-wave LDS RAW: waitcnt only)
#pragma unroll
        for (int it = 0; it < 4; it++) {
            int lr = it * 8 + (lane >> 3);            // local row 0..31
            int ch = (lane & 7) * 8;                  // 8 ushorts
            int grow = rowbase + lr;
            if (grow < N)
                __builtin_nontemporal_store(*(const us8*)&stage[wave][lr][ch],
                                            (us8*)(y + (size_t)grow * C + ch));
        }
        __syncthreads();   // dsh/cnt reused next bucket
    }
}

// ---------------- 3: aggregate: 4 nodes per wave (16 lanes each), lane = channel-quad -----
// (unchanged — bound by random 128B-gather service; instruction-count halvings proven
//  neutral in rounds 0->1 and 4->5)
__global__ __launch_bounds__(256) void k_aggregate(const int* __restrict__ rowptr, const int* __restrict__ deg,
                                                   const int* __restrict__ es, const unsigned short* __restrict__ y,
                                                   const float* __restrict__ b, float* __restrict__ out, int N) {
    int p = blockIdx.x & (NPART - 1);
    int j = blockIdx.x >> 3;
    int node = p * PS + j * 16 + (threadIdx.x >> 4);  // 16 nodes per block, 4 per wave
    int lim = (p + 1) * PS < N ? (p + 1) * PS : N;
    if (node >= lim) return;
    int chq = threadIdx.x & 15;                       // channel-quad index 0..15

    const uint2* yq = (const uint2*)y;                // y row = 16 uint2 (128 B)
    int m = deg[node];
    const int* sl = es + rowptr[node];

    uint2 us = yq[(unsigned)node * 16u + chq];        // self-loop
    float a0 = BF2L(us.x), a1 = BF2H(us.x), a2 = BF2L(us.y), a3 = BF2H(us.y);

    int e = 0;
    while (e + 16 <= m) {
        ix4 i0 = *(const ix4*)(sl + e);
        ix4 i1 = *(const ix4*)(sl + e + 4);
        ix4 i2 = *(const ix4*)(sl + e + 8);
        ix4 i3 = *(const ix4*)(sl + e + 12);
        uint2 u0 = yq[(unsigned)i0[0] * 16u + chq], u1 = yq[(unsigned)i0[1] * 16u + chq];
        uint2 u2 = yq[(unsigned)i0[2] * 16u + chq], u3 = yq[(unsigned)i0[3] * 16u + chq];
        uint2 u4 = yq[(unsigned)i1[0] * 16u + chq], u5 = yq[(unsigned)i1[1] * 16u + chq];
        uint2 u6 = yq[(unsigned)i1[2] * 16u + chq], u7 = yq[(unsigned)i1[3] * 16u + chq];
        uint2 u8 = yq[(unsigned)i2[0] * 16u + chq], u9 = yq[(unsigned)i2[1] * 16u + chq];
        uint2 u10 = yq[(unsigned)i2[2] * 16u + chq], u11 = yq[(unsigned)i2[3] * 16u + chq];
        uint2 u12 = yq[(unsigned)i3[0] * 16u + chq], u13 = yq[(unsigned)i3[1] * 16u + chq];
        uint2 u14 = yq[(unsigned)i3[2] * 16u + chq], u15 = yq[(unsigned)i3[3] * 16u + chq];
        a0 += ((BF2L(u0.x) + BF2L(u1.x)) + (BF2L(u2.x) + BF2L(u3.x))) +
              ((BF2L(u4.x) + BF2L(u5.x)) + (BF2L(u6.x) + BF2L(u7.x))) +
              ((BF2L(u8.x) + BF2L(u9.x)) + (BF2L(u10.x) + BF2L(u11.x))) +
              ((BF2L(u12.x) + BF2L(u13.x)) + (BF2L(u14.x) + BF2L(u15.x)));
        a1 += ((BF2H(u0.x) + BF2H(u1.x)) + (BF2H(u2.x) + BF2H(u3.x))) +
              ((BF2H(u4.x) + BF2H(u5.x)) + (BF2H(u6.x) + BF2H(u7.x))) +
              ((BF2H(u8.x) + BF2H(u9.x)) + (BF2H(u10.x) + BF2H(u11.x))) +
              ((BF2H(u12.x) + BF2H(u13.x)) + (BF2H(u14.x) + BF2H(u15.x)));
        a2 += ((BF2L(u0.y) + BF2L(u1.y)) + (BF2L(u2.y) + BF2L(u3.y))) +
              ((BF2L(u4.y) + BF2L(u5.y)) + (BF2L(u6.y) + BF2L(u7.y))) +
              ((BF2L(u8.y) + BF2L(u9.y)) + (BF2L(u10.y) + BF2L(u11.y))) +
              ((BF2L(u12.y) + BF2L(u13.y)) + (BF2L(u14.y) + BF2L(u15.y)));
        a3 += ((BF2H(u0.y) + BF2H(u1.y)) + (BF2H(u2.y) + BF2H(u3.y))) +
              ((BF2H(u4.y) + BF2H(u5.y)) + (BF2H(u6.y) + BF2H(u7.y))) +
              ((BF2H(u8.y) + BF2H(u9.y)) + (BF2H(u10.y) + BF2H(u11.y))) +
              ((BF2H(u12.y) + BF2H(u13.y)) + (BF2H(u14.y) + BF2H(u15.y)));
        e += 16;
    }
    if (e + 8 <= m) {
        ix4 i0 = *(const ix4*)(sl + e);
        ix4 i1 = *(const ix4*)(sl + e + 4);
        uint2 u0 = yq[(unsigned)i0[0] * 16u + chq], u1 = yq[(unsigned)i0[1] * 16u + chq];
        uint2 u2 = yq[(unsigned)i0[2] * 16u + chq], u3 = yq[(unsigned)i0[3] * 16u + chq];
        uint2 u4 = yq[(unsigned)i1[0] * 16u + chq], u5 = yq[(unsigned)i1[1] * 16u + chq];
        uint2 u6 = yq[(unsigned)i1[2] * 16u + chq], u7 = yq[(unsigned)i1[3] * 16u + chq];
        a0 += ((BF2L(u0.x) + BF2L(u1.x)) + (BF2L(u2.x) + BF2L(u3.x))) +
              ((BF2L(u4.x) + BF2L(u5.x)) + (BF2L(u6.x) + BF2L(u7.x)));
        a1 += ((BF2H(u0.x) + BF2H(u1.x)) + (BF2H(u2.x) + BF2H(u3.x))) +
              ((BF2H(u4.x) + BF2H(u5.x)) + (BF2H(u6.x) + BF2H(u7.x)));
        a2 += ((BF2L(u0.y) + BF2L(u1.y)) + (BF2L(u2.y) + BF2L(u3.y))) +
              ((BF2L(u4.y) + BF2L(u5.y)) + (BF2L(u6.y) + BF2L(u7.y)));
        a3 += ((BF2H(u0.y) + BF2H(u1.y)) + (BF2H(u2.y) + BF2H(u3.y))) +
              ((BF2H(u4.y) + BF2H(u5.y)) + (BF2H(u6.y) + BF2H(u7.y)));
        e += 8;
    }
    if (e + 4 <= m) {
        ix4 i0 = *(const ix4*)(sl + e);
        uint2 u0 = yq[(unsigned)i0[0] * 16u + chq], u1 = yq[(unsigned)i0[1] * 16u + chq];
        uint2 u2 = yq[(unsigned)i0[2] * 16u + chq], u3 = yq[(unsigned)i0[3] * 16u + chq];
        a0 += (BF2L(u0.x) + BF2L(u1.x)) + (BF2L(u2.x) + BF2L(u3.x));
        a1 += (BF2H(u0.x) + BF2H(u1.x)) + (BF2H(u2.x) + BF2H(u3.x));
        a2 += (BF2L(u0.y) + BF2L(u1.y)) + (BF2L(u2.y) + BF2L(u3.y));
        a3 += (BF2H(u0.y) + BF2H(u1.y)) + (BF2H(u2.y) + BF2H(u3.y));
        e += 4;
    }
    while (e < m) {
        uint2 u = yq[(unsigned)sl[e] * 16u + chq];
        a0 += BF2L(u.x); a1 += BF2H(u.x);
        a2 += BF2L(u.y); a3 += BF2H(u.y);
        e++;
    }

    float dn = rsqrtf((float)(m + 1));
    fx4 bb = *(const fx4*)(b + (chq << 2));
    fx4 o = {dn * a0 + bb[0], dn * a1 + bb[1], dn * a2 + bb[2], dn * a3 + bb[3]};
    __builtin_nontemporal_store(o, (fx4*)(out + (size_t)node * C) + chq);
}

extern "C" void kernel_launch(void* const* d_in, const int* in_sizes, int n_in,
                              void* d_out, int out_size, void* d_ws, size_t ws_size,
                              hipStream_t stream) {
    const float* x  = (const float*)d_in[0];
    const int*   ei = (const int*)d_in[1];
    const float* W  = (const float*)d_in[2];
    const float* b  = (const float*)d_in[3];
    float* out = (float*)d_out;

    const int N = in_sizes[0] / C;   // 100000
    const int E = in_sizes[1] / 2;   // 1600000
    const int* row = ei;             // sources
    const int* col = ei + E;         // targets

    const int nblk = (E + EPB2 - 1) / EPB2;  // 196

    // workspace: [bcur|wcnt] (one memset) | deg | rowptr | Wf | pe | es | y   (~30 MB)
    char* ws = (char*)d_ws;
    size_t o = 0;
    int* bcur   = (int*)(ws + o);
    int* wcnt   = bcur + NBUK;
    o += ((size_t)(NBUK + 1) * 4 + 127) & ~(size_t)127;
    int* deg    = (int*)(ws + o); o += ((size_t)N * 4 + 127) & ~(size_t)127;
    int* rowptr = (int*)(ws + o); o += ((size_t)N * 4 + 127) & ~(size_t)127;
    bh8* Wf     = (bh8*)(ws + o); o += 16 * 64 * 16;
    int* pe     = (int*)(ws + o); o += ((size_t)NBUK * BCAP * 4 + 127) & ~(size_t)127;
    int* es     = (int*)(ws + o); o += ((size_t)NBUK * BCAP * 4 + 127) & ~(size_t)127;
    unsigned short* y = (unsigned short*)(ws + o);

    hipMemsetAsync(bcur, 0, (size_t)(NBUK + 1) * 4, stream);
    k_bin<<<nblk, 256, 0, stream>>>(row, col, bcur, pe, E, W, Wf);
    k_sort2proj<<<S2P_GRID, 256, 0, stream>>>(pe, bcur, wcnt, es, rowptr, deg, x, Wf, y, N);
    k_aggregate<<<NPART * (PS / 16), 256, 0, stream>>>(rowptr, deg, es, y, b, out, N);
}

// Round 11
// 157.282 us; speedup vs baseline: 1.0291x; 1.0291x over previous
//
#include <hip/hip_runtime.h>
#include <hip/hip_bf16.h>

#define C 64          // C_IN == C_OUT == 64
#define BSH 7         // bucket shift: 128 nodes per bucket
#define BN  128       // nodes per bucket
#define NPART 8       // partitions == XCDs (agg node->block mapping)
#define PBUK 98       // buckets per partition (8*98=784 >= 782)
#define PS (PBUK*BN)  // nodes per partition = 12544
#define NBUK 784      // total buckets
#define EPB2 8192     // edges per k_bin block (256 thr x 32)
#define BCAP 2560     // bucket capacity (mean 2046, ~12 sigma)

typedef __attribute__((ext_vector_type(8))) short bh8;    // 8 bf16 (MFMA A/B frag)
typedef __attribute__((ext_vector_type(4))) float fx4;    // MFMA C/D frag
typedef __attribute__((ext_vector_type(4))) int   ix4;
typedef __attribute__((ext_vector_type(8))) unsigned short us8;

__device__ __forceinline__ unsigned short f2bf(float f) {  // RNE f32 -> bf16
    unsigned u = __float_as_uint(f);
    u += 0x7FFF + ((u >> 16) & 1);
    return (unsigned short)(u >> 16);
}
__device__ __forceinline__ float bf2f(unsigned short h) {
    return __uint_as_float(((unsigned)h) << 16);
}
#define BF2L(u) __uint_as_float((u) << 16)
#define BF2H(u) __uint_as_float((u) & 0xFFFF0000u)

// ---------------- 1: single-pass 784-way bin: edges -> pe[bucket*BCAP + rank] -------------
// Best-measured configuration (round 6, 157.9us): 196 blocks x 256 thr x 32 edges.
// Block 0 also builds the split-bf16 W fragments for k_sort2proj.
__global__ __launch_bounds__(256) void k_bin(const int* __restrict__ row, const int* __restrict__ col,
                                             int* __restrict__ bcur, int* __restrict__ pe, int E,
                                             const float* __restrict__ W, bh8* __restrict__ Wf) {
    __shared__ int h[NBUK];
    __shared__ int cur[NBUK];
    int tid = threadIdx.x;
    for (int i = tid; i < NBUK; i += 256) h[i] = 0;
    __syncthreads();

    int base = blockIdx.x * EPB2;
    int cs[32], rs[32];
    if (base + EPB2 <= E) {
#pragma unroll
        for (int ch = 0; ch < 8; ch++) {           // coalesced: lanes contiguous 16B
            int idx = base + ch * 1024 + (tid << 2);
            ix4 c = *(const ix4*)(col + idx);
            ix4 r = *(const ix4*)(row + idx);
#pragma unroll
            for (int k = 0; k < 4; k++) { cs[ch * 4 + k] = c[k]; rs[ch * 4 + k] = r[k]; }
        }
    } else {
#pragma unroll
        for (int i = 0; i < 32; i++) {
            int idx = base + (i >> 2) * 1024 + (tid << 2) + (i & 3);
            cs[i] = (idx < E) ? col[idx] : -1;
            rs[i] = (idx < E) ? row[idx] : 0;
        }
    }
#pragma unroll
    for (int i = 0; i < 32; i++)
        if (cs[i] >= 0) atomicAdd(&h[cs[i] >> BSH], 1);
    __syncthreads();
    for (int i = tid; i < NBUK; i += 256) {
        int c = h[i];
        cur[i] = (c > 0) ? atomicAdd(&bcur[i], c) : 0;
    }
    __syncthreads();
#pragma unroll
    for (int i = 0; i < 32; i++) {
        if (cs[i] >= 0) {
            int b = cs[i] >> BSH;
            int pos = atomicAdd(&cur[b], 1);
            if (pos < BCAP)
                pe[(size_t)b * BCAP + pos] = ((cs[i] & (BN - 1)) << 17) | rs[i];  // trel<<17|src
        }
    }

    // block 0: build Wf (split-bf16 W fragments); ready before k_sort2proj runs
    if (blockIdx.x == 0) {
        for (int it = tid; it < 512; it += 256) {
            int lane = it & 63;
            int th = it >> 6;        // t*2+h, 0..7
            int t = th >> 1, hh = th & 1;
            int m16 = lane & 15, q = lane >> 4;
            int n = t * 16 + m16;
            bh8 hi, lo;
#pragma unroll
            for (int j = 0; j < 8; j++) {
                int k = 32 * hh + q * 8 + j;
                float w = W[k * 64 + n];
                unsigned short hb = f2bf(w);
                hi[j] = (short)hb;
                lo[j] = (short)f2bf(w - bf2f(hb));
            }
            Wf[(th * 2 + 0) * 64 + lane] = hi;
            Wf[(th * 2 + 1) * 64 + lane] = lo;
        }
    }
}

// ---------------- 2: fused bucket->CSR + MFMA projection for the bucket's 128 nodes --------
// Phase 1 (de-staged): hist on first pe read, counting-sort scatter on second read (bucket
// slice is 8 KB, L2-hot after pass A). LDS 17.5 KB. Phase 2: y[r] = (x[r]@W) * rsqrt(deg+1)
// via split-bf16 MFMA, y stored via LDS stage.
__global__ __launch_bounds__(256) void k_sort2proj(const int* __restrict__ pe, const int* __restrict__ bcur,
                                                   int* __restrict__ es, int* __restrict__ rowptr,
                                                   int* __restrict__ deg, const float* __restrict__ x,
                                                   const bh8* __restrict__ Wf, unsigned short* __restrict__ y,
                                                   int N) {
    __shared__ int cnt[BN];
    __shared__ int cur[BN];
    __shared__ int dsh[BN];
    __shared__ unsigned short stage[4][32][C];    // 16 KB (per-wave private)

    int b = blockIdx.x;
    int tid = threadIdx.x;
    if (tid < BN) cnt[tid] = 0;
    __syncthreads();
    int m = bcur[b]; m = m < BCAP ? m : BCAP;
    size_t s0 = (size_t)b * BCAP;
    const int* peb = pe + s0;

    // pass A: histogram (vectorized read)
    for (int e0 = tid * 4; e0 < m; e0 += 1024) {
        if (e0 + 4 <= m) {
            ix4 a = *(const ix4*)(peb + e0);
#pragma unroll
            for (int k = 0; k < 4; k++) atomicAdd(&cnt[a[k] >> 17], 1);
        } else {
            for (int e = e0; e < m; e++) atomicAdd(&cnt[peb[e] >> 17], 1);
        }
    }
    __syncthreads();
    int v = (tid < BN) ? cnt[tid] : 0;
    for (int off = 1; off < BN; off <<= 1) {
        int t = (tid < BN && tid >= off) ? cnt[tid - off] : 0;
        __syncthreads();
        if (tid < BN) cnt[tid] += t;
        __syncthreads();
    }
    if (tid < BN) {
        int excl = cnt[tid] - v;
        cur[tid] = (int)s0 + excl;
        dsh[tid] = v;
        int node = b * BN + tid;
        if (node < N) { rowptr[node] = (int)s0 + excl; deg[node] = v; }
    }
    __syncthreads();
    // pass B: counting-sort scatter (pe re-read from L2)
    for (int e0 = tid * 4; e0 < m; e0 += 1024) {
        if (e0 + 4 <= m) {
            ix4 a = *(const ix4*)(peb + e0);
#pragma unroll
            for (int k = 0; k < 4; k++) {
                int pos = atomicAdd(&cur[a[k] >> 17], 1);
                es[pos] = a[k] & 0x1FFFF;
            }
        } else {
            for (int e = e0; e < m; e++) {
                int p = peb[e];
                int pos = atomicAdd(&cur[p >> 17], 1);
                es[pos] = p & 0x1FFFF;
            }
        }
    }
    __syncthreads();

    // ---- phase 2: projection of nodes b*BN .. b*BN+127 ----
    int lane = tid & 63;
    int wave = tid >> 6;
    int m16 = lane & 15;
    int q   = lane >> 4;

    bh8 Bhi[4][2], Blo[4][2];
#pragma unroll
    for (int t = 0; t < 4; t++) {
#pragma unroll
        for (int h = 0; h < 2; h++) {
            Bhi[t][h] = Wf[((t * 2 + h) * 2 + 0) * 64 + lane];  // coalesced dwordx4
            Blo[t][h] = Wf[((t * 2 + h) * 2 + 1) * 64 + lane];
        }
    }

    int rowbase = b * BN + wave * 32;
#pragma unroll
    for (int tt = 0; tt < 2; tt++) {
        int m0 = rowbase + tt * 16;
        if (m0 < N) {
            int mrow = m0 + m16;
            int mc = mrow < N ? mrow : (N - 1);

            bh8 Ahi[2], Alo[2];
#pragma unroll
            for (int h = 0; h < 2; h++) {
                const fx4* p = (const fx4*)(x + (size_t)mc * C + 32 * h + q * 8);
                fx4 v0 = __builtin_nontemporal_load(p);
                fx4 v1 = __builtin_nontemporal_load(p + 1);
                float vs[8] = {v0[0], v0[1], v0[2], v0[3], v1[0], v1[1], v1[2], v1[3]};
#pragma unroll
                for (int j = 0; j < 8; j++) {
                    unsigned short hb = f2bf(vs[j]);
                    Ahi[h][j] = (short)hb;
                    Alo[h][j] = (short)f2bf(vs[j] - bf2f(hb));
                }
            }

            float dv[4];
#pragma unroll
            for (int r = 0; r < 4; r++) {
                int lr = wave * 32 + tt * 16 + q * 4 + r;  // local row
                dv[r] = rsqrtf((float)(dsh[lr] + 1));
            }

#pragma unroll
            for (int t = 0; t < 4; t++) {
                fx4 acc = {0.f, 0.f, 0.f, 0.f};
#pragma unroll
                for (int h = 0; h < 2; h++) {
                    acc = __builtin_amdgcn_mfma_f32_16x16x32_bf16(Ahi[h], Bhi[t][h], acc, 0, 0, 0);
                    acc = __builtin_amdgcn_mfma_f32_16x16x32_bf16(Ahi[h], Blo[t][h], acc, 0, 0, 0);
                    acc = __builtin_amdgcn_mfma_f32_16x16x32_bf16(Alo[h], Bhi[t][h], acc, 0, 0, 0);
                }
#pragma unroll
                for (int r = 0; r < 4; r++)
                    stage[wave][tt * 16 + q * 4 + r][t * 16 + m16] = f2bf(acc[r] * dv[r]);
            }
        }
    }
    // wave-local stage->global, 16 B/lane coalesced (same-wave LDS RAW: waitcnt only)
#pragma unroll
    for (int it = 0; it < 4; it++) {
        int lr = it * 8 + (lane >> 3);            // local row 0..31
        int ch = (lane & 7) * 8;                  // 8 ushorts
        int grow = rowbase + lr;
        if (grow < N)
            __builtin_nontemporal_store(*(const us8*)&stage[wave][lr][ch],
                                        (us8*)(y + (size_t)grow * C + ch));
    }
}

// ---------------- 3: aggregate: 4 nodes per wave (16 lanes each), lane = channel-quad -----
// (bound by random 128B-gather service; instruction-count halvings proven neutral in
//  rounds 0->1 and 4->5)
__global__ __launch_bounds__(256) void k_aggregate(const int* __restrict__ rowptr, const int* __restrict__ deg,
                                                   const int* __restrict__ es, const unsigned short* __restrict__ y,
                                                   const float* __restrict__ b, float* __restrict__ out, int N) {
    int p = blockIdx.x & (NPART - 1);
    int j = blockIdx.x >> 3;
    int node = p * PS + j * 16 + (threadIdx.x >> 4);  // 16 nodes per block, 4 per wave
    int lim = (p + 1) * PS < N ? (p + 1) * PS : N;
    if (node >= lim) return;
    int chq = threadIdx.x & 15;                       // channel-quad index 0..15

    const uint2* yq = (const uint2*)y;                // y row = 16 uint2 (128 B)
    int m = deg[node];
    const int* sl = es + rowptr[node];

    uint2 us = yq[(unsigned)node * 16u + chq];        // self-loop
    float a0 = BF2L(us.x), a1 = BF2H(us.x), a2 = BF2L(us.y), a3 = BF2H(us.y);

    int e = 0;
    while (e + 16 <= m) {
        ix4 i0 = *(const ix4*)(sl + e);
        ix4 i1 = *(const ix4*)(sl + e + 4);
        ix4 i2 = *(const ix4*)(sl + e + 8);
        ix4 i3 = *(const ix4*)(sl + e + 12);
        uint2 u0 = yq[(unsigned)i0[0] * 16u + chq], u1 = yq[(unsigned)i0[1] * 16u + chq];
        uint2 u2 = yq[(unsigned)i0[2] * 16u + chq], u3 = yq[(unsigned)i0[3] * 16u + chq];
        uint2 u4 = yq[(unsigned)i1[0] * 16u + chq], u5 = yq[(unsigned)i1[1] * 16u + chq];
        uint2 u6 = yq[(unsigned)i1[2] * 16u + chq], u7 = yq[(unsigned)i1[3] * 16u + chq];
        uint2 u8 = yq[(unsigned)i2[0] * 16u + chq], u9 = yq[(unsigned)i2[1] * 16u + chq];
        uint2 u10 = yq[(unsigned)i2[2] * 16u + chq], u11 = yq[(unsigned)i2[3] * 16u + chq];
        uint2 u12 = yq[(unsigned)i3[0] * 16u + chq], u13 = yq[(unsigned)i3[1] * 16u + chq];
        uint2 u14 = yq[(unsigned)i3[2] * 16u + chq], u15 = yq[(unsigned)i3[3] * 16u + chq];
        a0 += ((BF2L(u0.x) + BF2L(u1.x)) + (BF2L(u2.x) + BF2L(u3.x))) +
              ((BF2L(u4.x) + BF2L(u5.x)) + (BF2L(u6.x) + BF2L(u7.x))) +
              ((BF2L(u8.x) + BF2L(u9.x)) + (BF2L(u10.x) + BF2L(u11.x))) +
              ((BF2L(u12.x) + BF2L(u13.x)) + (BF2L(u14.x) + BF2L(u15.x)));
        a1 += ((BF2H(u0.x) + BF2H(u1.x)) + (BF2H(u2.x) + BF2H(u3.x))) +
              ((BF2H(u4.x) + BF2H(u5.x)) + (BF2H(u6.x) + BF2H(u7.x))) +
              ((BF2H(u8.x) + BF2H(u9.x)) + (BF2H(u10.x) + BF2H(u11.x))) +
              ((BF2H(u12.x) + BF2H(u13.x)) + (BF2H(u14.x) + BF2H(u15.x)));
        a2 += ((BF2L(u0.y) + BF2L(u1.y)) + (BF2L(u2.y) + BF2L(u3.y))) +
              ((BF2L(u4.y) + BF2L(u5.y)) + (BF2L(u6.y) + BF2L(u7.y))) +
              ((BF2L(u8.y) + BF2L(u9.y)) + (BF2L(u10.y) + BF2L(u11.y))) +
              ((BF2L(u12.y) + BF2L(u13.y)) + (BF2L(u14.y) + BF2L(u15.y)));
        a3 += ((BF2H(u0.y) + BF2H(u1.y)) + (BF2H(u2.y) + BF2H(u3.y))) +
              ((BF2H(u4.y) + BF2H(u5.y)) + (BF2H(u6.y) + BF2H(u7.y))) +
              ((BF2H(u8.y) + BF2H(u9.y)) + (BF2H(u10.y) + BF2H(u11.y))) +
              ((BF2H(u12.y) + BF2H(u13.y)) + (BF2H(u14.y) + BF2H(u15.y)));
        e += 16;
    }
    if (e + 8 <= m) {
        ix4 i0 = *(const ix4*)(sl + e);
        ix4 i1 = *(const ix4*)(sl + e + 4);
        uint2 u0 = yq[(unsigned)i0[0] * 16u + chq], u1 = yq[(unsigned)i0[1] * 16u + chq];
        uint2 u2 = yq[(unsigned)i0[2] * 16u + chq], u3 = yq[(unsigned)i0[3] * 16u + chq];
        uint2 u4 = yq[(unsigned)i1[0] * 16u + chq], u5 = yq[(unsigned)i1[1] * 16u + chq];
        uint2 u6 = yq[(unsigned)i1[2] * 16u + chq], u7 = yq[(unsigned)i1[3] * 16u + chq];
        a0 += ((BF2L(u0.x) + BF2L(u1.x)) + (BF2L(u2.x) + BF2L(u3.x))) +
              ((BF2L(u4.x) + BF2L(u5.x)) + (BF2L(u6.x) + BF2L(u7.x)));
        a1 += ((BF2H(u0.x) + BF2H(u1.x)) + (BF2H(u2.x) + BF2H(u3.x))) +
              ((BF2H(u4.x) + BF2H(u5.x)) + (BF2H(u6.x) + BF2H(u7.x)));
        a2 += ((BF2L(u0.y) + BF2L(u1.y)) + (BF2L(u2.y) + BF2L(u3.y))) +
              ((BF2L(u4.y) + BF2L(u5.y)) + (BF2L(u6.y) + BF2L(u7.y)));
        a3 += ((BF2H(u0.y) + BF2H(u1.y)) + (BF2H(u2.y) + BF2H(u3.y))) +
              ((BF2H(u4.y) + BF2H(u5.y)) + (BF2H(u6.y) + BF2H(u7.y)));
        e += 8;
    }
    if (e + 4 <= m) {
        ix4 i0 = *(const ix4*)(sl + e);
        uint2 u0 = yq[(unsigned)i0[0] * 16u + chq], u1 = yq[(unsigned)i0[1] * 16u + chq];
        uint2 u2 = yq[(unsigned)i0[2] * 16u + chq], u3 = yq[(unsigned)i0[3] * 16u + chq];
        a0 += (BF2L(u0.x) + BF2L(u1.x)) + (BF2L(u2.x) + BF2L(u3.x));
        a1 += (BF2H(u0.x) + BF2H(u1.x)) + (BF2H(u2.x) + BF2H(u3.x));
        a2 += (BF2L(u0.y) + BF2L(u1.y)) + (BF2L(u2.y) + BF2L(u3.y));
        a3 += (BF2H(u0.y) + BF2H(u1.y)) + (BF2H(u2.y) + BF2H(u3.y));
        e += 4;
    }
    while (e < m) {
        uint2 u = yq[(unsigned)sl[e] * 16u + chq];
        a0 += BF2L(u.x); a1 += BF2H(u.x);
        a2 += BF2L(u.y); a3 += BF2H(u.y);
        e++;
    }

    float dn = rsqrtf((float)(m + 1));
    fx4 bb = *(const fx4*)(b + (chq << 2));
    fx4 o = {dn * a0 + bb[0], dn * a1 + bb[1], dn * a2 + bb[2], dn * a3 + bb[3]};
    __builtin_nontemporal_store(o, (fx4*)(out + (size_t)node * C) + chq);
}

extern "C" void kernel_launch(void* const* d_in, const int* in_sizes, int n_in,
                              void* d_out, int out_size, void* d_ws, size_t ws_size,
                              hipStream_t stream) {
    const float* x  = (const float*)d_in[0];
    const int*   ei = (const int*)d_in[1];
    const float* W  = (const float*)d_in[2];
    const float* b  = (const float*)d_in[3];
    float* out = (float*)d_out;

    const int N = in_sizes[0] / C;   // 100000
    const int E = in_sizes[1] / 2;   // 1600000
    const int* row = ei;             // sources
    const int* col = ei + E;         // targets

    const int nblk = (E + EPB2 - 1) / EPB2;  // 196

    // workspace: bcur (memset) | deg | rowptr | Wf | pe | es | y   (~30 MB)
    char* ws = (char*)d_ws;
    size_t o = 0;
    int* bcur   = (int*)(ws + o); o += ((size_t)NBUK * 4 + 127) & ~(size_t)127;
    int* deg    = (int*)(ws + o); o += ((size_t)N * 4 + 127) & ~(size_t)127;
    int* rowptr = (int*)(ws + o); o += ((size_t)N * 4 + 127) & ~(size_t)127;
    bh8* Wf     = (bh8*)(ws + o); o += 16 * 64 * 16;
    int* pe     = (int*)(ws + o); o += ((size_t)NBUK * BCAP * 4 + 127) & ~(size_t)127;
    int* es     = (int*)(ws + o); o += ((size_t)NBUK * BCAP * 4 + 127) & ~(size_t)127;
    unsigned short* y = (unsigned short*)(ws + o);

    hipMemsetAsync(bcur, 0, (size_t)NBUK * 4, stream);
    k_bin<<<nblk, 256, 0, stream>>>(row, col, bcur, pe, E, W, Wf);
    k_sort2proj<<<NBUK, 256, 0, stream>>>(pe, bcur, es, rowptr, deg, x, Wf, y, N);
    k_aggregate<<<NPART * (PS / 16), 256, 0, stream>>>(rowptr, deg, es, y, b, out, N);
}